// Round 13
// baseline (917.660 us; speedup 1.0000x reference)
//
#include <hip/hip_runtime.h>

#define NPTS 16384
#define GRID 32             // cells per axis (cell width 0.25)
#define SGRID 16            // superblocks per axis (width 0.5)
#define NCELL 32768         // 32^3
#define CS_STRIDE (NCELL+1)
#define GLO -4.0f
#define GH 0.25f
#define GINVH 4.0f
#define SBW 0.5f            // superblock width

// sets: 0 = xyz1[b=0], 1 = xyz1[b=1], 2 = xyz2[b=0], 3 = xyz2[b=1]
// ws layout (bytes):
//   float4 spts[4][NPTS]            @ 0        (1048576)  Morton-sorted, w = |p|^2 (exact rn chain)
//   int    sidx[4][NPTS]            @ 1048576  (262144)
//   int    cellStart[4][NCELL+1]    @ 1310720  (524304)
//   int    hist[4][NCELL]           @ 1835024  (524288)
//   int    cursor[4][NCELL]         @ 2359312  (524288)
// total 2883600 bytes

__device__ __forceinline__ int clampg(int v){ return v<0?0:(v>GRID-1?GRID-1:v); }
__device__ __forceinline__ int spr5(int v){           // 5-bit -> bits 0,3,6,9,12
    return (v&1) | ((v&2)<<2) | ((v&4)<<4) | ((v&8)<<6) | ((v&16)<<8);
}
__device__ __forceinline__ int spr4(int v){           // 4-bit -> bits 0,3,6,9
    return (v&1) | ((v&2)<<2) | ((v&4)<<4) | ((v&8)<<6);
}
__device__ __forceinline__ int mcode(int ix,int iy,int iz){
    return spr5(ix) | (spr5(iy)<<1) | (spr5(iz)<<2);  // 15-bit Morton
}

__global__ __launch_bounds__(256) void zero_hist(int* __restrict__ hist){
    hist[blockIdx.x*256 + threadIdx.x] = 0;           // grid 512 -> 131072 ints
}

__global__ __launch_bounds__(256) void bin_kernel(
    const float* __restrict__ xyz1, const float* __restrict__ xyz2,
    int* __restrict__ hist)
{
    int t = blockIdx.x*256 + threadIdx.x;             // 0..65535
    int s = t >> 14, i = t & (NPTS-1);
    const float* src = (s < 2 ? xyz1 : xyz2) + ((size_t)(s&1)*NPTS + i)*3;
    float x = src[0], y = src[1], z = src[2];
    int ix = clampg((int)floorf((x-GLO)*GINVH));
    int iy = clampg((int)floorf((y-GLO)*GINVH));
    int iz = clampg((int)floorf((z-GLO)*GINVH));
    atomicAdd(&hist[s*NCELL + mcode(ix,iy,iz)], 1);
}

// one block (1024 thr) per set: exclusive scan of 32768 counts (32/thread)
__global__ __launch_bounds__(1024) void scan_kernel(
    const int* __restrict__ hist, int* __restrict__ cellStart, int* __restrict__ cursor)
{
    int s = blockIdx.x, tid = threadIdx.x, lane = tid & 63, w = tid >> 6; // 16 waves
    const int* h = hist + s*NCELL;
    int v[32]; int tsum = 0;
    #pragma unroll
    for (int k = 0; k < 32; ++k) { v[k] = h[tid*32 + k]; tsum += v[k]; }
    int x = tsum;
    #pragma unroll
    for (int d = 1; d < 64; d <<= 1) { int y = __shfl_up(x, d, 64); if (lane >= d) x += y; }
    __shared__ int wsum[16];
    if (lane == 63) wsum[w] = x;
    __syncthreads();
    if (tid == 0) { int acc = 0; for (int i2 = 0; i2 < 16; ++i2) { int tt = wsum[i2]; wsum[i2] = acc; acc += tt; } }
    __syncthreads();
    int excl = x - tsum + wsum[w];
    int* cs = cellStart + s*CS_STRIDE;
    int* cu = cursor   + s*NCELL;
    #pragma unroll
    for (int k = 0; k < 32; ++k) { cs[tid*32+k] = excl; cu[tid*32+k] = excl; excl += v[k]; }
    if (tid == 1023) cs[NCELL] = excl;                // == NPTS
}

__global__ __launch_bounds__(256) void scatter_kernel(
    const float* __restrict__ xyz1, const float* __restrict__ xyz2,
    int* __restrict__ cursor, float4* __restrict__ spts, int* __restrict__ sidx)
{
    int t = blockIdx.x*256 + threadIdx.x;
    int s = t >> 14, i = t & (NPTS-1);
    const float* src = (s < 2 ? xyz1 : xyz2) + ((size_t)(s&1)*NPTS + i)*3;
    float x = src[0], y = src[1], z = src[2];
    float sq = __fadd_rn(__fadd_rn(__fmul_rn(x,x), __fmul_rn(y,y)), __fmul_rn(z,z));
    int ix = clampg((int)floorf((x-GLO)*GINVH));
    int iy = clampg((int)floorf((y-GLO)*GINVH));
    int iz = clampg((int)floorf((z-GLO)*GINVH));
    int code = mcode(ix,iy,iz);
    int pos = atomicAdd(&cursor[s*NCELL + code], 1);
    spts[s*NPTS + pos] = make_float4(x, y, z, sq);
    sidx[s*NPTS + pos] = i;
}

// 8 lanes per query, 8 queries per wave, 1 octet per wave (static, 8192 waves).
// Scan unit = SUPERBLOCK (2x2x2 cells of 0.25 => width 0.5): Morton-contiguous
// spts range, streamed stride-8 across sub-lanes, 4x-unrolled (8 outstanding loads).
// cs[] reads wave-uniform -> scalar-pipe s_loads (r11: NOT LDS).
// Exact key (bit-identical to rounds 2/5): t=fma(az,cz,fma(ay,cy,ax*cx)); d=fma(-2,t,rn(asq+bsq)).
// Lex-min (d, orig_idx) == np.argmin first-occurrence; conservative prune
// 0.995*LB - 3e-4 covers worst-case chain rounding; order-independent.
__global__ __launch_bounds__(256) void nn_kernel(
    const float4* __restrict__ spts, const int* __restrict__ sidx,
    const int* __restrict__ cellStart, float* __restrict__ out)
{
    const int gt   = blockIdx.x*256 + threadIdx.x;
    const int lane = gt & 63;
    const int wv   = gt >> 6;                 // 0..8191
    const int set  = wv >> 11;                // 0..3 = dir*2 + b
    const int dir  = set >> 1;
    const int b    = set & 1;
    const int qset = (dir == 0) ? b : 2 + b;
    const int cset = (dir == 0) ? 2 + b : b;
    const int qbase = (wv & 2047) << 3;       // 8 queries per wave
    const int qsub  = lane >> 3;              // 0..7: which query
    const int sub   = lane & 7;               // 0..7: candidate split
    const int qpos  = qbase + qsub;

    float4 q = spts[qset*NPTS + qpos];
    const int qorig = sidx[qset*NPTS + qpos];
    const float ax = q.x, ay = q.y, az = q.z, aw = q.w;

    int ix = clampg((int)floorf((ax-GLO)*GINVH));
    int iy = clampg((int)floorf((ay-GLO)*GINVH));
    int iz = clampg((int)floorf((az-GLO)*GINVH));

    // wave cell bounding box (8 distinct queries, duplicated x8)
    int bx0 = ix, bx1 = ix, by0 = iy, by1 = iy, bz0 = iz, bz1 = iz;
    #pragma unroll
    for (int m = 32; m; m >>= 1) {
        bx0 = min(bx0, __shfl_xor(bx0, m, 64)); bx1 = max(bx1, __shfl_xor(bx1, m, 64));
        by0 = min(by0, __shfl_xor(by0, m, 64)); by1 = max(by1, __shfl_xor(by1, m, 64));
        bz0 = min(bz0, __shfl_xor(bz0, m, 64)); bz1 = max(bz1, __shfl_xor(bz1, m, 64));
    }
    const int sx0 = __builtin_amdgcn_readfirstlane(bx0 >> 1);
    const int sx1 = __builtin_amdgcn_readfirstlane(bx1 >> 1);
    const int sy0 = __builtin_amdgcn_readfirstlane(by0 >> 1);
    const int sy1 = __builtin_amdgcn_readfirstlane(by1 >> 1);
    const int sz0 = __builtin_amdgcn_readfirstlane(bz0 >> 1);
    const int sz1 = __builtin_amdgcn_readfirstlane(bz1 >> 1);

    const float4* cp = spts + cset*NPTS;
    const int*    ci = sidx + cset*NPTS;
    const int*    cs = cellStart + cset*CS_STRIDE;

    float bd = __builtin_inff(); int bi = 0;

    #define EVAL(c4, cix)                                                        \
    {                                                                            \
        float tt = fmaf(az, (c4).z, fmaf(ay, (c4).y, __fmul_rn(ax, (c4).x)));    \
        float dd = fmaf(-2.0f, tt, __fadd_rn(aw, (c4).w));                       \
        bool bet = (dd < bd) || (dd == bd && (cix) < bi);                        \
        bd = bet ? dd : bd; bi = bet ? (cix) : bi;                               \
    }

    #define SCAN_RANGE(j0, j1)                                                   \
    {                                                                            \
        int j = (j0) + sub;                                                      \
        for (; j + 24 < (j1); j += 32) {                                         \
            float4 c0 = cp[j];    int i0 = ci[j];                                \
            float4 c1 = cp[j+8];  int i1 = ci[j+8];                              \
            float4 c2 = cp[j+16]; int i2 = ci[j+16];                             \
            float4 c3 = cp[j+24]; int i3 = ci[j+24];                             \
            EVAL(c0, i0); EVAL(c1, i1); EVAL(c2, i2); EVAL(c3, i3);              \
        }                                                                        \
        for (; j < (j1); j += 8) {                                               \
            float4 c4 = cp[j]; int cix = ci[j];                                  \
            EVAL(c4, cix);                                                       \
        }                                                                        \
    }

    // seed window around the wave's sorted position (Morton locality)
    {
        int s0 = qbase + 4 - 80; if (s0 < 0) s0 = 0;
        int e0 = s0 + 160;       if (e0 > NPTS) { e0 = NPTS; s0 = e0 - 160; }
        s0 = __builtin_amdgcn_readfirstlane(s0);
        e0 = __builtin_amdgcn_readfirstlane(e0);
        SCAN_RANGE(s0, e0);
    }

    // superblock (0.5 width) Chebyshev shells outward
    for (int s = 0; s <= 2*SGRID; ++s) {
        int zlo = max(0, sz0 - s), zhi = min(SGRID-1, sz1 + s);
        int ylo = max(0, sy0 - s), yhi = min(SGRID-1, sy1 + s);
        int xlo = max(0, sx0 - s), xhi = min(SGRID-1, sx1 + s);
        for (int scz = zlo; scz <= zhi; ++scz) {
            int cdz = max(0, max(sz0 - scz, scz - sz1));
            float lo = (scz == 0)       ? -1e30f : (GLO + (float)(scz*2    )*GH);
            float hi = (scz == SGRID-1) ?  1e30f : (GLO + (float)(scz*2 + 2)*GH);
            float dzz = fmaxf(0.0f, fmaxf(lo - az, az - hi));
            float dz2 = __fmul_rn(dzz, dzz);
            for (int scy = ylo; scy <= yhi; ++scy) {
                int cdy = max(cdz, max(0, max(sy0 - scy, scy - sy1)));
                if (cdy > s) continue;
                lo = (scy == 0)       ? -1e30f : (GLO + (float)(scy*2    )*GH);
                hi = (scy == SGRID-1) ?  1e30f : (GLO + (float)(scy*2 + 2)*GH);
                float dyy = fmaxf(0.0f, fmaxf(lo - ay, ay - hi));
                float dyz2 = fmaf(dyy, dyy, dz2);
                int sbyz = (spr4(scy)<<1) | (spr4(scz)<<2);
                for (int scx = xlo; scx <= xhi; ++scx) {
                    int cd = max(cdy, max(0, max(sx0 - scx, scx - sx1)));
                    if (cd != s) continue;
                    lo = (scx == 0)       ? -1e30f : (GLO + (float)(scx*2    )*GH);
                    hi = (scx == SGRID-1) ?  1e30f : (GLO + (float)(scx*2 + 2)*GH);
                    float dxx = fmaxf(0.0f, fmaxf(lo - ax, ax - hi));
                    float lb = fmaf(dxx, dxx, dyz2);
                    if (__ballot(fmaf(0.995f, lb, -3e-4f) <= bd) == 0ULL) continue;
                    int sb = spr4(scx) | sbyz;
                    int j0 = __builtin_amdgcn_readfirstlane(cs[sb<<3]);
                    int j1 = __builtin_amdgcn_readfirstlane(cs[(sb+1)<<3]);
                    SCAN_RANGE(j0, j1);
                }
            }
        }
        float wmax = bd;
        #pragma unroll
        for (int m = 32; m; m >>= 1) wmax = fmaxf(wmax, __shfl_xor(wmax, m, 64));
        float rs = (float)s * SBW;            // unvisited: Euclid >= s * 0.5
        if (fmaf(0.995f, __fmul_rn(rs, rs), -3e-4f) > wmax) break;
        if (xlo == 0 && ylo == 0 && zlo == 0 &&
            xhi == SGRID-1 && yhi == SGRID-1 && zhi == SGRID-1) break; // grid covered
    }

    #undef SCAN_RANGE
    #undef EVAL

    // reduce the 8 sub-lanes of each query: lex-min (d, orig_idx)
    #pragma unroll
    for (int m = 1; m < 8; m <<= 1) {
        float od = __shfl_xor(bd, m, 64);
        int   oi = __shfl_xor(bi, m, 64);
        bool bet = (od < bd) || (od == bd && oi < bi);
        bd = bet ? od : bd; bi = bet ? oi : bi;
    }

    if (sub == 0) {
        int off  = dir ? 32768 : 0;
        int slot = b*NPTS + qorig;
        out[off + slot]         = bd;
        out[65536 + off + slot] = (float)bi;
    }
}

// fallback (no/small ws): brute force, exact chain
__global__ __launch_bounds__(256) void nn_full(
    const float* __restrict__ xyz1, const float* __restrict__ xyz2,
    float* __restrict__ out)
{
    int qid = blockIdx.x*256 + threadIdx.x;
    int dir = qid >> 15;
    int q15 = qid & 32767;
    const float* qsrc = dir ? xyz2 : xyz1;
    float ax = qsrc[q15*3+0], ay = qsrc[q15*3+1], az = qsrc[q15*3+2];
    float asq = __fadd_rn(__fadd_rn(__fmul_rn(ax,ax), __fmul_rn(ay,ay)), __fmul_rn(az,az));
    const float* cp = (dir ? xyz1 : xyz2) + (size_t)(q15 & NPTS)*3;
    float bd = 3.402823466e+38f; int bi = 0;
    for (int j = 0; j < NPTS; ++j) {
        float bx = cp[3*j+0], by = cp[3*j+1], bz = cp[3*j+2];
        float bsq = __fadd_rn(__fadd_rn(__fmul_rn(bx,bx), __fmul_rn(by,by)), __fmul_rn(bz,bz));
        float tt = fmaf(az, bz, fmaf(ay, by, __fmul_rn(ax, bx)));
        float d = fmaf(-2.0f, tt, __fadd_rn(asq, bsq));
        if (d < bd) { bd = d; bi = j; }
    }
    int off = dir ? 32768 : 0;
    out[off + q15]         = bd;
    out[65536 + off + q15] = (float)bi;
}

extern "C" void kernel_launch(void* const* d_in, const int* in_sizes, int n_in,
                              void* d_out, int out_size, void* d_ws, size_t ws_size,
                              hipStream_t stream) {
    const float* xyz1 = (const float*)d_in[0];
    const float* xyz2 = (const float*)d_in[1];
    float* out = (float*)d_out;

    const size_t off_spts = 0;
    const size_t off_sidx = 1048576;
    const size_t off_cs   = 1310720;
    const size_t off_hist = 1835024;
    const size_t off_cur  = 2359312;
    const size_t need     = 2883600;

    if (d_ws != nullptr && ws_size >= need) {
        float4* spts = (float4*)((char*)d_ws + off_spts);
        int* sidx    = (int*)((char*)d_ws + off_sidx);
        int* cstart  = (int*)((char*)d_ws + off_cs);
        int* hist    = (int*)((char*)d_ws + off_hist);
        int* cursor  = (int*)((char*)d_ws + off_cur);
        zero_hist   <<<512, 256, 0, stream>>>(hist);
        bin_kernel  <<<256, 256, 0, stream>>>(xyz1, xyz2, hist);
        scan_kernel <<<4,  1024, 0, stream>>>(hist, cstart, cursor);
        scatter_kernel<<<256,256,0, stream>>>(xyz1, xyz2, cursor, spts, sidx);
        nn_kernel   <<<2048, 256, 0, stream>>>(spts, sidx, cstart, out);
    } else {
        nn_full<<<65536/256, 256, 0, stream>>>(xyz1, xyz2, out);
    }
}

// Round 14
// 247.118 us; speedup vs baseline: 3.7135x; 3.7135x over previous
//
#include <hip/hip_runtime.h>

#define NPTS 16384
#define GRID 16
#define SGRID 8
#define NCELL 4096          // 16^3
#define CS_STRIDE (NCELL+1)
#define GLO -4.0f
#define GH 0.5f
#define GINVH 2.0f

// sets: 0 = xyz1[b=0], 1 = xyz1[b=1], 2 = xyz2[b=0], 3 = xyz2[b=1]
// ws layout (bytes):
//   float4 spts[4][NPTS]            @ 0        (1048576)  Morton-sorted, w = |p|^2 (exact rn chain)
//   int    sidx[4][NPTS]            @ 1048576  (262144)
//   int    cellStart[4][NCELL+1]    @ 1310720  (65552)
//   int    hist[4][NCELL]           @ 1376272  (65536)
//   int    cursor[4][NCELL]         @ 1441808  (65536)
// total 1507344 bytes

__device__ __forceinline__ int clamp16(int v){ return v<0?0:(v>15?15:v); }
__device__ __forceinline__ int spr3(int v){           // 4-bit -> bits 0,3,6,9
    return (v&1) | ((v&2)<<2) | ((v&4)<<4) | ((v&8)<<6);
}
__device__ __forceinline__ int mcode(int ix,int iy,int iz){
    return spr3(ix) | (spr3(iy)<<1) | (spr3(iz)<<2);  // 12-bit Morton
}

__global__ __launch_bounds__(256) void zero_hist(int* __restrict__ hist){
    hist[blockIdx.x*256 + threadIdx.x] = 0;           // grid 64 -> 16384 ints
}

__global__ __launch_bounds__(256) void bin_kernel(
    const float* __restrict__ xyz1, const float* __restrict__ xyz2,
    int* __restrict__ hist)
{
    int t = blockIdx.x*256 + threadIdx.x;             // 0..65535
    int s = t >> 14, i = t & (NPTS-1);
    const float* src = (s < 2 ? xyz1 : xyz2) + ((size_t)(s&1)*NPTS + i)*3;
    float x = src[0], y = src[1], z = src[2];
    int ix = clamp16((int)floorf((x-GLO)*GINVH));
    int iy = clamp16((int)floorf((y-GLO)*GINVH));
    int iz = clamp16((int)floorf((z-GLO)*GINVH));
    atomicAdd(&hist[s*NCELL + mcode(ix,iy,iz)], 1);
}

// one block (1024 thr) per set: exclusive scan of 4096 counts
__global__ __launch_bounds__(1024) void scan_kernel(
    const int* __restrict__ hist, int* __restrict__ cellStart, int* __restrict__ cursor)
{
    int s = blockIdx.x, tid = threadIdx.x, lane = tid & 63, w = tid >> 6; // 16 waves
    const int* h = hist + s*NCELL;
    int v0 = h[tid*4+0], v1 = h[tid*4+1], v2 = h[tid*4+2], v3 = h[tid*4+3];
    int tsum = v0+v1+v2+v3;
    int x = tsum;
    #pragma unroll
    for (int d = 1; d < 64; d <<= 1) { int y = __shfl_up(x, d, 64); if (lane >= d) x += y; }
    __shared__ int wsum[16];
    if (lane == 63) wsum[w] = x;
    __syncthreads();
    if (tid == 0) { int acc = 0; for (int i2 = 0; i2 < 16; ++i2) { int tt = wsum[i2]; wsum[i2] = acc; acc += tt; } }
    __syncthreads();
    int excl = x - tsum + wsum[w];
    int* cs = cellStart + s*CS_STRIDE;
    int* cu = cursor   + s*NCELL;
    cs[tid*4+0] = excl; cu[tid*4+0] = excl; excl += v0;
    cs[tid*4+1] = excl; cu[tid*4+1] = excl; excl += v1;
    cs[tid*4+2] = excl; cu[tid*4+2] = excl; excl += v2;
    cs[tid*4+3] = excl; cu[tid*4+3] = excl; excl += v3;
    if (tid == 1023) cs[NCELL] = excl;                // == NPTS
}

__global__ __launch_bounds__(256) void scatter_kernel(
    const float* __restrict__ xyz1, const float* __restrict__ xyz2,
    int* __restrict__ cursor, float4* __restrict__ spts, int* __restrict__ sidx)
{
    int t = blockIdx.x*256 + threadIdx.x;
    int s = t >> 14, i = t & (NPTS-1);
    const float* src = (s < 2 ? xyz1 : xyz2) + ((size_t)(s&1)*NPTS + i)*3;
    float x = src[0], y = src[1], z = src[2];
    float sq = __fadd_rn(__fadd_rn(__fmul_rn(x,x), __fmul_rn(y,y)), __fmul_rn(z,z));
    int ix = clamp16((int)floorf((x-GLO)*GINVH));
    int iy = clamp16((int)floorf((y-GLO)*GINVH));
    int iz = clamp16((int)floorf((z-GLO)*GINVH));
    int code = mcode(ix,iy,iz);
    int pos = atomicAdd(&cursor[s*NCELL + code], 1);
    spts[s*NPTS + pos] = make_float4(x, y, z, sq);
    sidx[s*NPTS + pos] = i;
}

// 8 lanes per query, 8 queries per wave, static octet per wave (8192 waves).
// Traverse at SUPERBLOCK level (2x2x2 cells, width 1.0, Morton-contiguous);
// inside a passing superblock, load its 9 contiguous cell offsets (one scalar
// batch) and prune per CELL (width 0.5) before scanning -- fine rejection
// without extra dependent-lookup round-trips (r13 lesson).
// cs[] reads wave-uniform -> scalar pipe (r11 lesson: not LDS).
// Exact key (bit-identical to rounds 2/5): t=fma(az,cz,fma(ay,cy,ax*cx)); d=fma(-2,t,rn(asq+bsq)).
// Lex-min (d, orig_idx) == np.argmin first-occurrence; conservative prune
// 0.995*LB - 3e-4 covers worst-case chain rounding; order-independent.
__global__ __launch_bounds__(256) void nn_kernel(
    const float4* __restrict__ spts, const int* __restrict__ sidx,
    const int* __restrict__ cellStart, float* __restrict__ out)
{
    const int gt   = blockIdx.x*256 + threadIdx.x;
    const int lane = gt & 63;
    const int wv   = gt >> 6;                 // 0..8191
    const int set  = wv >> 11;                // 0..3 = dir*2 + b
    const int dir  = set >> 1;
    const int b    = set & 1;
    const int qset = (dir == 0) ? b : 2 + b;
    const int cset = (dir == 0) ? 2 + b : b;
    const int qbase = (wv & 2047) << 3;       // 8 queries per wave
    const int qsub  = lane >> 3;              // 0..7: which query
    const int sub   = lane & 7;               // 0..7: candidate split
    const int qpos  = qbase + qsub;

    float4 q = spts[qset*NPTS + qpos];
    const int qorig = sidx[qset*NPTS + qpos];
    const float ax = q.x, ay = q.y, az = q.z, aw = q.w;

    int ix = clamp16((int)floorf((ax-GLO)*GINVH));
    int iy = clamp16((int)floorf((ay-GLO)*GINVH));
    int iz = clamp16((int)floorf((az-GLO)*GINVH));

    // wave cell bounding box (8 distinct queries, duplicated x8)
    int bx0 = ix, bx1 = ix, by0 = iy, by1 = iy, bz0 = iz, bz1 = iz;
    #pragma unroll
    for (int m = 32; m; m >>= 1) {
        bx0 = min(bx0, __shfl_xor(bx0, m, 64)); bx1 = max(bx1, __shfl_xor(bx1, m, 64));
        by0 = min(by0, __shfl_xor(by0, m, 64)); by1 = max(by1, __shfl_xor(by1, m, 64));
        bz0 = min(bz0, __shfl_xor(bz0, m, 64)); bz1 = max(bz1, __shfl_xor(bz1, m, 64));
    }
    const int sx0 = __builtin_amdgcn_readfirstlane(bx0 >> 1);
    const int sx1 = __builtin_amdgcn_readfirstlane(bx1 >> 1);
    const int sy0 = __builtin_amdgcn_readfirstlane(by0 >> 1);
    const int sy1 = __builtin_amdgcn_readfirstlane(by1 >> 1);
    const int sz0 = __builtin_amdgcn_readfirstlane(bz0 >> 1);
    const int sz1 = __builtin_amdgcn_readfirstlane(bz1 >> 1);

    const float4* cp = spts + cset*NPTS;
    const int*    ci = sidx + cset*NPTS;
    const int*    cs = cellStart + cset*CS_STRIDE;

    float bd = __builtin_inff(); int bi = 0;

    #define EVAL(c4, cix)                                                        \
    {                                                                            \
        float tt = fmaf(az, (c4).z, fmaf(ay, (c4).y, __fmul_rn(ax, (c4).x)));    \
        float dd = fmaf(-2.0f, tt, __fadd_rn(aw, (c4).w));                       \
        bool bet = (dd < bd) || (dd == bd && (cix) < bi);                        \
        bd = bet ? dd : bd; bi = bet ? (cix) : bi;                               \
    }

    #define SCAN_RANGE(j0, j1)                                                   \
    {                                                                            \
        int j = (j0) + sub;                                                      \
        for (; j + 24 < (j1); j += 32) {                                         \
            float4 c0 = cp[j];    int i0 = ci[j];                                \
            float4 c1 = cp[j+8];  int i1 = ci[j+8];                              \
            float4 c2 = cp[j+16]; int i2 = ci[j+16];                             \
            float4 c3 = cp[j+24]; int i3 = ci[j+24];                             \
            EVAL(c0, i0); EVAL(c1, i1); EVAL(c2, i2); EVAL(c3, i3);              \
        }                                                                        \
        for (; j < (j1); j += 8) {                                               \
            float4 c4 = cp[j]; int cix = ci[j];                                  \
            EVAL(c4, cix);                                                       \
        }                                                                        \
    }

    // seed window around the wave's sorted position (Morton locality)
    {
        int s0 = qbase + 4 - 80; if (s0 < 0) s0 = 0;
        int e0 = s0 + 160;       if (e0 > NPTS) { e0 = NPTS; s0 = e0 - 160; }
        s0 = __builtin_amdgcn_readfirstlane(s0);
        e0 = __builtin_amdgcn_readfirstlane(e0);
        SCAN_RANGE(s0, e0);
    }

    // superblock (2x2x2 cells, width 1.0) Chebyshev shells outward
    for (int s = 0; s <= 8; ++s) {
        int zlo = max(0, sz0 - s), zhi = min(SGRID-1, sz1 + s);
        int ylo = max(0, sy0 - s), yhi = min(SGRID-1, sy1 + s);
        int xlo = max(0, sx0 - s), xhi = min(SGRID-1, sx1 + s);
        for (int scz = zlo; scz <= zhi; ++scz) {
            int cdz = max(0, max(sz0 - scz, scz - sz1));
            // superblock-level z distance (edge -> infinite, clamped outliers)
            float lo = (scz == 0)       ? -1e30f : (GLO + (float)(scz*2    )*GH);
            float hi = (scz == SGRID-1) ?  1e30f : (GLO + (float)(scz*2 + 2)*GH);
            float dzz = fmaxf(0.0f, fmaxf(lo - az, az - hi));
            float dz2 = __fmul_rn(dzz, dzz);
            // sub-cell z distances (cells 2*scz, 2*scz+1)
            float zl0 = (scz == 0)       ? -1e30f : (GLO + (float)(scz*2    )*GH);
            float zh0 =                              GLO + (float)(scz*2 + 1)*GH;
            float zl1 =                              GLO + (float)(scz*2 + 1)*GH;
            float zh1 = (scz == SGRID-1) ?  1e30f : (GLO + (float)(scz*2 + 2)*GH);
            float dzc0 = fmaxf(0.0f, fmaxf(zl0 - az, az - zh0)); float dz0q = dzc0*dzc0;
            float dzc1 = fmaxf(0.0f, fmaxf(zl1 - az, az - zh1)); float dz1q = dzc1*dzc1;
            for (int scy = ylo; scy <= yhi; ++scy) {
                int cdy = max(cdz, max(0, max(sy0 - scy, scy - sy1)));
                if (cdy > s) continue;
                lo = (scy == 0)       ? -1e30f : (GLO + (float)(scy*2    )*GH);
                hi = (scy == SGRID-1) ?  1e30f : (GLO + (float)(scy*2 + 2)*GH);
                float dyy = fmaxf(0.0f, fmaxf(lo - ay, ay - hi));
                float dyz2 = fmaf(dyy, dyy, dz2);
                float yl0 = (scy == 0)       ? -1e30f : (GLO + (float)(scy*2    )*GH);
                float yh0 =                              GLO + (float)(scy*2 + 1)*GH;
                float yh1 = (scy == SGRID-1) ?  1e30f : (GLO + (float)(scy*2 + 2)*GH);
                float dyc0 = fmaxf(0.0f, fmaxf(yl0 - ay, ay - yh0)); float dy0q = dyc0*dyc0;
                float dyc1 = fmaxf(0.0f, fmaxf(yh0 - ay, ay - yh1)); float dy1q = dyc1*dyc1;
                int sbyz = (spr3(scy)<<1) | (spr3(scz)<<2);
                for (int scx = xlo; scx <= xhi; ++scx) {
                    int cd = max(cdy, max(0, max(sx0 - scx, scx - sx1)));
                    if (cd != s) continue;
                    lo = (scx == 0)       ? -1e30f : (GLO + (float)(scx*2    )*GH);
                    hi = (scx == SGRID-1) ?  1e30f : (GLO + (float)(scx*2 + 2)*GH);
                    float dxx = fmaxf(0.0f, fmaxf(lo - ax, ax - hi));
                    float lb = fmaf(dxx, dxx, dyz2);
                    if (__ballot(fmaf(0.995f, lb, -3e-4f) <= bd) == 0ULL) continue;
                    // cell offsets: 9 contiguous wave-uniform ints (one scalar batch)
                    int sb = spr3(scx) | sbyz;
                    int base = sb << 3;
                    int o[9];
                    #pragma unroll
                    for (int k = 0; k < 9; ++k)
                        o[k] = __builtin_amdgcn_readfirstlane(cs[base + k]);
                    // sub-cell x distances
                    float xl0 = (scx == 0)       ? -1e30f : (GLO + (float)(scx*2    )*GH);
                    float xh0 =                              GLO + (float)(scx*2 + 1)*GH;
                    float xh1 = (scx == SGRID-1) ?  1e30f : (GLO + (float)(scx*2 + 2)*GH);
                    float dxc0 = fmaxf(0.0f, fmaxf(xl0 - ax, ax - xh0)); float dx0q = dxc0*dxc0;
                    float dxc1 = fmaxf(0.0f, fmaxf(xh0 - ax, ax - xh1)); float dx1q = dxc1*dxc1;
                    // per-cell prune + scan (c = Morton sub-index: x=bit0,y=bit1,z=bit2)
                    #pragma unroll
                    for (int c = 0; c < 8; ++c) {
                        float clb = ((c&1) ? dx1q : dx0q)
                                  + ((c&2) ? dy1q : dy0q)
                                  + ((c&4) ? dz1q : dz0q);
                        if (__ballot(fmaf(0.995f, clb, -3e-4f) <= bd) == 0ULL) continue;
                        SCAN_RANGE(o[c], o[c+1]);
                    }
                }
            }
        }
        float wmax = bd;
        #pragma unroll
        for (int m = 32; m; m >>= 1) wmax = fmaxf(wmax, __shfl_xor(wmax, m, 64));
        float rs = (float)s;                  // unvisited: Euclid >= s * 1.0
        if (fmaf(0.995f, rs*rs, -3e-4f) > wmax) break;
        if (xlo == 0 && ylo == 0 && zlo == 0 &&
            xhi == SGRID-1 && yhi == SGRID-1 && zhi == SGRID-1) break; // grid covered
    }

    #undef SCAN_RANGE
    #undef EVAL

    // reduce the 8 sub-lanes of each query: lex-min (d, orig_idx)
    #pragma unroll
    for (int m = 1; m < 8; m <<= 1) {
        float od = __shfl_xor(bd, m, 64);
        int   oi = __shfl_xor(bi, m, 64);
        bool bet = (od < bd) || (od == bd && oi < bi);
        bd = bet ? od : bd; bi = bet ? oi : bi;
    }

    if (sub == 0) {
        int off  = dir ? 32768 : 0;
        int slot = b*NPTS + qorig;
        out[off + slot]         = bd;
        out[65536 + off + slot] = (float)bi;
    }
}

// fallback (no/small ws): brute force, exact chain
__global__ __launch_bounds__(256) void nn_full(
    const float* __restrict__ xyz1, const float* __restrict__ xyz2,
    float* __restrict__ out)
{
    int qid = blockIdx.x*256 + threadIdx.x;
    int dir = qid >> 15;
    int q15 = qid & 32767;
    const float* qsrc = dir ? xyz2 : xyz1;
    float ax = qsrc[q15*3+0], ay = qsrc[q15*3+1], az = qsrc[q15*3+2];
    float asq = __fadd_rn(__fadd_rn(__fmul_rn(ax,ax), __fmul_rn(ay,ay)), __fmul_rn(az,az));
    const float* cp = (dir ? xyz1 : xyz2) + (size_t)(q15 & NPTS)*3;
    float bd = 3.402823466e+38f; int bi = 0;
    for (int j = 0; j < NPTS; ++j) {
        float bx = cp[3*j+0], by = cp[3*j+1], bz = cp[3*j+2];
        float bsq = __fadd_rn(__fadd_rn(__fmul_rn(bx,bx), __fmul_rn(by,by)), __fmul_rn(bz,bz));
        float tt = fmaf(az, bz, fmaf(ay, by, __fmul_rn(ax, bx)));
        float d = fmaf(-2.0f, tt, __fadd_rn(asq, bsq));
        if (d < bd) { bd = d; bi = j; }
    }
    int off = dir ? 32768 : 0;
    out[off + q15]         = bd;
    out[65536 + off + q15] = (float)bi;
}

extern "C" void kernel_launch(void* const* d_in, const int* in_sizes, int n_in,
                              void* d_out, int out_size, void* d_ws, size_t ws_size,
                              hipStream_t stream) {
    const float* xyz1 = (const float*)d_in[0];
    const float* xyz2 = (const float*)d_in[1];
    float* out = (float*)d_out;

    const size_t off_spts = 0;
    const size_t off_sidx = 1048576;
    const size_t off_cs   = 1310720;
    const size_t off_hist = 1376272;
    const size_t off_cur  = 1441808;
    const size_t need     = 1507344;

    if (d_ws != nullptr && ws_size >= need) {
        float4* spts = (float4*)((char*)d_ws + off_spts);
        int* sidx    = (int*)((char*)d_ws + off_sidx);
        int* cstart  = (int*)((char*)d_ws + off_cs);
        int* hist    = (int*)((char*)d_ws + off_hist);
        int* cursor  = (int*)((char*)d_ws + off_cur);
        zero_hist   <<<64,  256, 0, stream>>>(hist);
        bin_kernel  <<<256, 256, 0, stream>>>(xyz1, xyz2, hist);
        scan_kernel <<<4,  1024, 0, stream>>>(hist, cstart, cursor);
        scatter_kernel<<<256,256,0, stream>>>(xyz1, xyz2, cursor, spts, sidx);
        nn_kernel   <<<2048, 256, 0, stream>>>(spts, sidx, cstart, out);
    } else {
        nn_full<<<65536/256, 256, 0, stream>>>(xyz1, xyz2, out);
    }
}

// Round 15
// 192.912 us; speedup vs baseline: 4.7569x; 1.2810x over previous
//
#include <hip/hip_runtime.h>

#define NPTS 16384
#define GRID 16
#define SGRID 8
#define NCELL 4096          // 16^3
#define CS_STRIDE (NCELL+1)
#define GLO -4.0f
#define GH 0.5f
#define GINVH 2.0f

// sets: 0 = xyz1[b=0], 1 = xyz1[b=1], 2 = xyz2[b=0], 3 = xyz2[b=1]
// ws layout (bytes):
//   float4 spts[4][NPTS]            @ 0        (1048576)  Morton-sorted, w = |p|^2 (exact rn chain)
//   int    sidx[4][NPTS]            @ 1048576  (262144)
//   int    cellStart[4][NCELL+1]    @ 1310720  (65552)
//   int    hist[4][NCELL]           @ 1376272  (65536)
//   int    cursor[4][NCELL]         @ 1441808  (65536)
// total 1507344 bytes

__device__ __forceinline__ int clamp16(int v){ return v<0?0:(v>15?15:v); }
__device__ __forceinline__ int spr3(int v){           // 4-bit -> bits 0,3,6,9
    return (v&1) | ((v&2)<<2) | ((v&4)<<4) | ((v&8)<<6);
}
__device__ __forceinline__ int mcode(int ix,int iy,int iz){
    return spr3(ix) | (spr3(iy)<<1) | (spr3(iz)<<2);  // 12-bit Morton
}

__global__ __launch_bounds__(256) void zero_hist(int* __restrict__ hist){
    hist[blockIdx.x*256 + threadIdx.x] = 0;           // grid 64 -> 16384 ints
}

__global__ __launch_bounds__(256) void bin_kernel(
    const float* __restrict__ xyz1, const float* __restrict__ xyz2,
    int* __restrict__ hist)
{
    int t = blockIdx.x*256 + threadIdx.x;             // 0..65535
    int s = t >> 14, i = t & (NPTS-1);
    const float* src = (s < 2 ? xyz1 : xyz2) + ((size_t)(s&1)*NPTS + i)*3;
    float x = src[0], y = src[1], z = src[2];
    int ix = clamp16((int)floorf((x-GLO)*GINVH));
    int iy = clamp16((int)floorf((y-GLO)*GINVH));
    int iz = clamp16((int)floorf((z-GLO)*GINVH));
    atomicAdd(&hist[s*NCELL + mcode(ix,iy,iz)], 1);
}

// one block (1024 thr) per set: exclusive scan of 4096 counts
__global__ __launch_bounds__(1024) void scan_kernel(
    const int* __restrict__ hist, int* __restrict__ cellStart, int* __restrict__ cursor)
{
    int s = blockIdx.x, tid = threadIdx.x, lane = tid & 63, w = tid >> 6; // 16 waves
    const int* h = hist + s*NCELL;
    int v0 = h[tid*4+0], v1 = h[tid*4+1], v2 = h[tid*4+2], v3 = h[tid*4+3];
    int tsum = v0+v1+v2+v3;
    int x = tsum;
    #pragma unroll
    for (int d = 1; d < 64; d <<= 1) { int y = __shfl_up(x, d, 64); if (lane >= d) x += y; }
    __shared__ int wsum[16];
    if (lane == 63) wsum[w] = x;
    __syncthreads();
    if (tid == 0) { int acc = 0; for (int i2 = 0; i2 < 16; ++i2) { int tt = wsum[i2]; wsum[i2] = acc; acc += tt; } }
    __syncthreads();
    int excl = x - tsum + wsum[w];
    int* cs = cellStart + s*CS_STRIDE;
    int* cu = cursor   + s*NCELL;
    cs[tid*4+0] = excl; cu[tid*4+0] = excl; excl += v0;
    cs[tid*4+1] = excl; cu[tid*4+1] = excl; excl += v1;
    cs[tid*4+2] = excl; cu[tid*4+2] = excl; excl += v2;
    cs[tid*4+3] = excl; cu[tid*4+3] = excl; excl += v3;
    if (tid == 1023) cs[NCELL] = excl;                // == NPTS
}

__global__ __launch_bounds__(256) void scatter_kernel(
    const float* __restrict__ xyz1, const float* __restrict__ xyz2,
    int* __restrict__ cursor, float4* __restrict__ spts, int* __restrict__ sidx)
{
    int t = blockIdx.x*256 + threadIdx.x;
    int s = t >> 14, i = t & (NPTS-1);
    const float* src = (s < 2 ? xyz1 : xyz2) + ((size_t)(s&1)*NPTS + i)*3;
    float x = src[0], y = src[1], z = src[2];
    float sq = __fadd_rn(__fadd_rn(__fmul_rn(x,x), __fmul_rn(y,y)), __fmul_rn(z,z));
    int ix = clamp16((int)floorf((x-GLO)*GINVH));
    int iy = clamp16((int)floorf((y-GLO)*GINVH));
    int iz = clamp16((int)floorf((z-GLO)*GINVH));
    int code = mcode(ix,iy,iz);
    int pos = atomicAdd(&cursor[s*NCELL + code], 1);
    spts[s*NPTS + pos] = make_float4(x, y, z, sq);
    sidx[s*NPTS + pos] = i;
}

// 16 lanes per query, 4 queries per wave -> 16384 waves (4096 blocks, 2x
// oversubscribed: second-round blocks backfill as light waves retire).
// Tighter 4-query union -> better ballot pruning + earlier termination;
// dense ranges split /16 -> straggler waves ~2x faster.
// Scan unit = SUPERBLOCK (2x2x2 cells, Morton-contiguous), stride-16 across
// sub-lanes, 4x-unrolled (8 outstanding loads). cs[] wave-uniform -> scalar pipe.
// Exact key (bit-identical to rounds 2/5): t=fma(az,cz,fma(ay,cy,ax*cx)); d=fma(-2,t,rn(asq+bsq)).
// Lex-min (d, orig_idx) == np.argmin first-occurrence; conservative prune
// 0.995*LB - 3e-4 covers worst-case chain rounding; order-independent.
__global__ __launch_bounds__(256) void nn_kernel(
    const float4* __restrict__ spts, const int* __restrict__ sidx,
    const int* __restrict__ cellStart, float* __restrict__ out)
{
    const int gt   = blockIdx.x*256 + threadIdx.x;
    const int lane = gt & 63;
    const int wv   = gt >> 6;                 // 0..16383
    const int set  = wv >> 12;                // 0..3 = dir*2 + b
    const int dir  = set >> 1;
    const int b    = set & 1;
    const int qset = (dir == 0) ? b : 2 + b;
    const int cset = (dir == 0) ? 2 + b : b;
    const int qbase = (wv & 4095) << 2;       // 4 queries per wave
    const int qsub  = lane >> 4;              // 0..3: which query
    const int sub   = lane & 15;              // 0..15: candidate split
    const int qpos  = qbase + qsub;

    float4 q = spts[qset*NPTS + qpos];
    const int qorig = sidx[qset*NPTS + qpos];
    const float ax = q.x, ay = q.y, az = q.z, aw = q.w;

    int ix = clamp16((int)floorf((ax-GLO)*GINVH));
    int iy = clamp16((int)floorf((ay-GLO)*GINVH));
    int iz = clamp16((int)floorf((az-GLO)*GINVH));

    // wave cell bounding box (4 distinct queries, duplicated x16)
    int bx0 = ix, bx1 = ix, by0 = iy, by1 = iy, bz0 = iz, bz1 = iz;
    #pragma unroll
    for (int m = 32; m; m >>= 1) {
        bx0 = min(bx0, __shfl_xor(bx0, m, 64)); bx1 = max(bx1, __shfl_xor(bx1, m, 64));
        by0 = min(by0, __shfl_xor(by0, m, 64)); by1 = max(by1, __shfl_xor(by1, m, 64));
        bz0 = min(bz0, __shfl_xor(bz0, m, 64)); bz1 = max(bz1, __shfl_xor(bz1, m, 64));
    }
    const int sx0 = __builtin_amdgcn_readfirstlane(bx0 >> 1);
    const int sx1 = __builtin_amdgcn_readfirstlane(bx1 >> 1);
    const int sy0 = __builtin_amdgcn_readfirstlane(by0 >> 1);
    const int sy1 = __builtin_amdgcn_readfirstlane(by1 >> 1);
    const int sz0 = __builtin_amdgcn_readfirstlane(bz0 >> 1);
    const int sz1 = __builtin_amdgcn_readfirstlane(bz1 >> 1);

    const float4* cp = spts + cset*NPTS;
    const int*    ci = sidx + cset*NPTS;
    const int*    cs = cellStart + cset*CS_STRIDE;

    float bd = __builtin_inff(); int bi = 0;

    #define EVAL(c4, cix)                                                        \
    {                                                                            \
        float tt = fmaf(az, (c4).z, fmaf(ay, (c4).y, __fmul_rn(ax, (c4).x)));    \
        float dd = fmaf(-2.0f, tt, __fadd_rn(aw, (c4).w));                       \
        bool bet = (dd < bd) || (dd == bd && (cix) < bi);                        \
        bd = bet ? dd : bd; bi = bet ? (cix) : bi;                               \
    }

    // stride-16 scan of [j0,j1), 4x unrolled batched loads for MLP
    #define SCAN_RANGE(j0, j1)                                                   \
    {                                                                            \
        int j = (j0) + sub;                                                      \
        for (; j + 48 < (j1); j += 64) {                                         \
            float4 c0 = cp[j];    int i0 = ci[j];                                \
            float4 c1 = cp[j+16]; int i1 = ci[j+16];                             \
            float4 c2 = cp[j+32]; int i2 = ci[j+32];                             \
            float4 c3 = cp[j+48]; int i3 = ci[j+48];                             \
            EVAL(c0, i0); EVAL(c1, i1); EVAL(c2, i2); EVAL(c3, i3);              \
        }                                                                        \
        for (; j < (j1); j += 16) {                                              \
            float4 c4 = cp[j]; int cix = ci[j];                                  \
            EVAL(c4, cix);                                                       \
        }                                                                        \
    }

    // seed window around the wave's sorted position (Morton locality)
    {
        int s0 = qbase + 2 - 80; if (s0 < 0) s0 = 0;
        int e0 = s0 + 160;       if (e0 > NPTS) { e0 = NPTS; s0 = e0 - 160; }
        s0 = __builtin_amdgcn_readfirstlane(s0);
        e0 = __builtin_amdgcn_readfirstlane(e0);
        SCAN_RANGE(s0, e0);
    }

    // superblock (2x2x2 cells, width 1.0) Chebyshev shells outward
    for (int s = 0; s <= 8; ++s) {
        int zlo = max(0, sz0 - s), zhi = min(SGRID-1, sz1 + s);
        int ylo = max(0, sy0 - s), yhi = min(SGRID-1, sy1 + s);
        int xlo = max(0, sx0 - s), xhi = min(SGRID-1, sx1 + s);
        for (int scz = zlo; scz <= zhi; ++scz) {
            int cdz = max(0, max(sz0 - scz, scz - sz1));
            float lo = (scz == 0)       ? -1e30f : (GLO + (float)(scz*2    )*GH);
            float hi = (scz == SGRID-1) ?  1e30f : (GLO + (float)(scz*2 + 2)*GH);
            float dzz = fmaxf(0.0f, fmaxf(lo - az, az - hi));
            float dz2 = __fmul_rn(dzz, dzz);
            for (int scy = ylo; scy <= yhi; ++scy) {
                int cdy = max(cdz, max(0, max(sy0 - scy, scy - sy1)));
                if (cdy > s) continue;
                lo = (scy == 0)       ? -1e30f : (GLO + (float)(scy*2    )*GH);
                hi = (scy == SGRID-1) ?  1e30f : (GLO + (float)(scy*2 + 2)*GH);
                float dyy = fmaxf(0.0f, fmaxf(lo - ay, ay - hi));
                float dyz2 = fmaf(dyy, dyy, dz2);
                int sbyz = (spr3(scy)<<1) | (spr3(scz)<<2);
                for (int scx = xlo; scx <= xhi; ++scx) {
                    int cd = max(cdy, max(0, max(sx0 - scx, scx - sx1)));
                    if (cd != s) continue;
                    lo = (scx == 0)       ? -1e30f : (GLO + (float)(scx*2    )*GH);
                    hi = (scx == SGRID-1) ?  1e30f : (GLO + (float)(scx*2 + 2)*GH);
                    float dxx = fmaxf(0.0f, fmaxf(lo - ax, ax - hi));
                    float lb = fmaf(dxx, dxx, dyz2);
                    if (__ballot(fmaf(0.995f, lb, -3e-4f) <= bd) == 0ULL) continue;
                    int sb = spr3(scx) | sbyz;
                    int j0 = __builtin_amdgcn_readfirstlane(cs[sb<<3]);
                    int j1 = __builtin_amdgcn_readfirstlane(cs[(sb+1)<<3]);
                    SCAN_RANGE(j0, j1);
                }
            }
        }
        float wmax = bd;
        #pragma unroll
        for (int m = 32; m; m >>= 1) wmax = fmaxf(wmax, __shfl_xor(wmax, m, 64));
        float rs = (float)s;                  // unvisited: Euclid >= s * 1.0
        if (fmaf(0.995f, rs*rs, -3e-4f) > wmax) break;
        if (xlo == 0 && ylo == 0 && zlo == 0 &&
            xhi == SGRID-1 && yhi == SGRID-1 && zhi == SGRID-1) break; // grid covered
    }

    #undef SCAN_RANGE
    #undef EVAL

    // reduce the 16 sub-lanes of each query: lex-min (d, orig_idx)
    #pragma unroll
    for (int m = 1; m < 16; m <<= 1) {
        float od = __shfl_xor(bd, m, 64);
        int   oi = __shfl_xor(bi, m, 64);
        bool bet = (od < bd) || (od == bd && oi < bi);
        bd = bet ? od : bd; bi = bet ? oi : bi;
    }

    if (sub == 0) {
        int off  = dir ? 32768 : 0;
        int slot = b*NPTS + qorig;
        out[off + slot]         = bd;
        out[65536 + off + slot] = (float)bi;
    }
}

// fallback (no/small ws): brute force, exact chain
__global__ __launch_bounds__(256) void nn_full(
    const float* __restrict__ xyz1, const float* __restrict__ xyz2,
    float* __restrict__ out)
{
    int qid = blockIdx.x*256 + threadIdx.x;
    int dir = qid >> 15;
    int q15 = qid & 32767;
    const float* qsrc = dir ? xyz2 : xyz1;
    float ax = qsrc[q15*3+0], ay = qsrc[q15*3+1], az = qsrc[q15*3+2];
    float asq = __fadd_rn(__fadd_rn(__fmul_rn(ax,ax), __fmul_rn(ay,ay)), __fmul_rn(az,az));
    const float* cp = (dir ? xyz1 : xyz2) + (size_t)(q15 & NPTS)*3;
    float bd = 3.402823466e+38f; int bi = 0;
    for (int j = 0; j < NPTS; ++j) {
        float bx = cp[3*j+0], by = cp[3*j+1], bz = cp[3*j+2];
        float bsq = __fadd_rn(__fadd_rn(__fmul_rn(bx,bx), __fmul_rn(by,by)), __fmul_rn(bz,bz));
        float tt = fmaf(az, bz, fmaf(ay, by, __fmul_rn(ax, bx)));
        float d = fmaf(-2.0f, tt, __fadd_rn(asq, bsq));
        if (d < bd) { bd = d; bi = j; }
    }
    int off = dir ? 32768 : 0;
    out[off + q15]         = bd;
    out[65536 + off + q15] = (float)bi;
}

extern "C" void kernel_launch(void* const* d_in, const int* in_sizes, int n_in,
                              void* d_out, int out_size, void* d_ws, size_t ws_size,
                              hipStream_t stream) {
    const float* xyz1 = (const float*)d_in[0];
    const float* xyz2 = (const float*)d_in[1];
    float* out = (float*)d_out;

    const size_t off_spts = 0;
    const size_t off_sidx = 1048576;
    const size_t off_cs   = 1310720;
    const size_t off_hist = 1376272;
    const size_t off_cur  = 1441808;
    const size_t need     = 1507344;

    if (d_ws != nullptr && ws_size >= need) {
        float4* spts = (float4*)((char*)d_ws + off_spts);
        int* sidx    = (int*)((char*)d_ws + off_sidx);
        int* cstart  = (int*)((char*)d_ws + off_cs);
        int* hist    = (int*)((char*)d_ws + off_hist);
        int* cursor  = (int*)((char*)d_ws + off_cur);
        zero_hist   <<<64,  256, 0, stream>>>(hist);
        bin_kernel  <<<256, 256, 0, stream>>>(xyz1, xyz2, hist);
        scan_kernel <<<4,  1024, 0, stream>>>(hist, cstart, cursor);
        scatter_kernel<<<256,256,0, stream>>>(xyz1, xyz2, cursor, spts, sidx);
        nn_kernel   <<<4096, 256, 0, stream>>>(spts, sidx, cstart, out);
    } else {
        nn_full<<<65536/256, 256, 0, stream>>>(xyz1, xyz2, out);
    }
}

// Round 16
// 180.226 us; speedup vs baseline: 5.0917x; 1.0704x over previous
//
#include <hip/hip_runtime.h>

#define NPTS 16384
#define GRID 16
#define SGRID 8
#define NCELL 4096          // 16^3
#define CS_STRIDE (NCELL+1)
#define GLO -4.0f
#define GH 0.5f
#define GINVH 2.0f

// sets: 0 = xyz1[b=0], 1 = xyz1[b=1], 2 = xyz2[b=0], 3 = xyz2[b=1]
// ws layout (bytes):
//   float4 spts[4][NPTS]            @ 0        (1048576)  Morton-sorted; w = __int_as_float(orig idx)
//   int    cellStart[4][NCELL+1]    @ 1048576  (65552)
//   int    hist[4][NCELL]           @ 1114128  (65536)
//   int    cursor[4][NCELL]         @ 1179664  (65536)
// total 1245200 bytes

__device__ __forceinline__ int clamp16(int v){ return v<0?0:(v>15?15:v); }
__device__ __forceinline__ int spr3(int v){           // 4-bit -> bits 0,3,6,9
    return (v&1) | ((v&2)<<2) | ((v&4)<<4) | ((v&8)<<6);
}
__device__ __forceinline__ int mcode(int ix,int iy,int iz){
    return spr3(ix) | (spr3(iy)<<1) | (spr3(iz)<<2);  // 12-bit Morton
}

__global__ __launch_bounds__(256) void zero_hist(int* __restrict__ hist){
    hist[blockIdx.x*256 + threadIdx.x] = 0;           // grid 64 -> 16384 ints
}

__global__ __launch_bounds__(256) void bin_kernel(
    const float* __restrict__ xyz1, const float* __restrict__ xyz2,
    int* __restrict__ hist)
{
    int t = blockIdx.x*256 + threadIdx.x;             // 0..65535
    int s = t >> 14, i = t & (NPTS-1);
    const float* src = (s < 2 ? xyz1 : xyz2) + ((size_t)(s&1)*NPTS + i)*3;
    float x = src[0], y = src[1], z = src[2];
    int ix = clamp16((int)floorf((x-GLO)*GINVH));
    int iy = clamp16((int)floorf((y-GLO)*GINVH));
    int iz = clamp16((int)floorf((z-GLO)*GINVH));
    atomicAdd(&hist[s*NCELL + mcode(ix,iy,iz)], 1);
}

// one block (1024 thr) per set: exclusive scan of 4096 counts
__global__ __launch_bounds__(1024) void scan_kernel(
    const int* __restrict__ hist, int* __restrict__ cellStart, int* __restrict__ cursor)
{
    int s = blockIdx.x, tid = threadIdx.x, lane = tid & 63, w = tid >> 6; // 16 waves
    const int* h = hist + s*NCELL;
    int v0 = h[tid*4+0], v1 = h[tid*4+1], v2 = h[tid*4+2], v3 = h[tid*4+3];
    int tsum = v0+v1+v2+v3;
    int x = tsum;
    #pragma unroll
    for (int d = 1; d < 64; d <<= 1) { int y = __shfl_up(x, d, 64); if (lane >= d) x += y; }
    __shared__ int wsum[16];
    if (lane == 63) wsum[w] = x;
    __syncthreads();
    if (tid == 0) { int acc = 0; for (int i2 = 0; i2 < 16; ++i2) { int tt = wsum[i2]; wsum[i2] = acc; acc += tt; } }
    __syncthreads();
    int excl = x - tsum + wsum[w];
    int* cs = cellStart + s*CS_STRIDE;
    int* cu = cursor   + s*NCELL;
    cs[tid*4+0] = excl; cu[tid*4+0] = excl; excl += v0;
    cs[tid*4+1] = excl; cu[tid*4+1] = excl; excl += v1;
    cs[tid*4+2] = excl; cu[tid*4+2] = excl; excl += v2;
    cs[tid*4+3] = excl; cu[tid*4+3] = excl; excl += v3;
    if (tid == 1023) cs[NCELL] = excl;                // == NPTS
}

__global__ __launch_bounds__(256) void scatter_kernel(
    const float* __restrict__ xyz1, const float* __restrict__ xyz2,
    int* __restrict__ cursor, float4* __restrict__ spts)
{
    int t = blockIdx.x*256 + threadIdx.x;
    int s = t >> 14, i = t & (NPTS-1);
    const float* src = (s < 2 ? xyz1 : xyz2) + ((size_t)(s&1)*NPTS + i)*3;
    float x = src[0], y = src[1], z = src[2];
    int ix = clamp16((int)floorf((x-GLO)*GINVH));
    int iy = clamp16((int)floorf((y-GLO)*GINVH));
    int iz = clamp16((int)floorf((z-GLO)*GINVH));
    int code = mcode(ix,iy,iz);
    int pos = atomicAdd(&cursor[s*NCELL + code], 1);
    spts[s*NPTS + pos] = make_float4(x, y, z, __int_as_float(i));  // idx packed in .w
}

// 8 lanes per query, 8 queries per wave, static octet per wave (8192 waves).
// Scan unit = SUPERBLOCK (2x2x2 cells, Morton-contiguous), stride-8 across
// sub-lanes, 4x-unrolled — now 1 load/eval (idx packed in .w, bsq recomputed
// in-register with the EXACT rn chain: rn(rn(x^2+y^2)+z^2), bit-identical to
// the precomputed value all passing rounds used).
// cs[] wave-uniform -> scalar pipe (r11: not LDS).
// Exact key (bit-identical to rounds 2/5): t=fma(az,cz,fma(ay,cy,ax*cx)); d=fma(-2,t,rn(asq+bsq)).
// Lex-min (d, orig_idx) == np.argmin first-occurrence; conservative prune
// 0.995*LB - 3e-4 covers worst-case chain rounding; order-independent.
__global__ __launch_bounds__(256) void nn_kernel(
    const float4* __restrict__ spts,
    const int* __restrict__ cellStart, float* __restrict__ out)
{
    const int gt   = blockIdx.x*256 + threadIdx.x;
    const int lane = gt & 63;
    const int wv   = gt >> 6;                 // 0..8191
    const int set  = wv >> 11;                // 0..3 = dir*2 + b
    const int dir  = set >> 1;
    const int b    = set & 1;
    const int qset = (dir == 0) ? b : 2 + b;
    const int cset = (dir == 0) ? 2 + b : b;
    const int qbase = (wv & 2047) << 3;       // 8 queries per wave
    const int qsub  = lane >> 3;              // 0..7: which query
    const int sub   = lane & 7;               // 0..7: candidate split
    const int qpos  = qbase + qsub;

    float4 q = spts[qset*NPTS + qpos];
    const int qorig = __float_as_int(q.w);
    const float ax = q.x, ay = q.y, az = q.z;
    // asq with the exact rn chain (matches prior rounds' precomputed value)
    const float aw = __fadd_rn(__fadd_rn(__fmul_rn(ax,ax), __fmul_rn(ay,ay)), __fmul_rn(az,az));

    int ix = clamp16((int)floorf((ax-GLO)*GINVH));
    int iy = clamp16((int)floorf((ay-GLO)*GINVH));
    int iz = clamp16((int)floorf((az-GLO)*GINVH));

    // wave cell bounding box (8 distinct queries, duplicated x8)
    int bx0 = ix, bx1 = ix, by0 = iy, by1 = iy, bz0 = iz, bz1 = iz;
    #pragma unroll
    for (int m = 32; m; m >>= 1) {
        bx0 = min(bx0, __shfl_xor(bx0, m, 64)); bx1 = max(bx1, __shfl_xor(bx1, m, 64));
        by0 = min(by0, __shfl_xor(by0, m, 64)); by1 = max(by1, __shfl_xor(by1, m, 64));
        bz0 = min(bz0, __shfl_xor(bz0, m, 64)); bz1 = max(bz1, __shfl_xor(bz1, m, 64));
    }
    const int sx0 = __builtin_amdgcn_readfirstlane(bx0 >> 1);
    const int sx1 = __builtin_amdgcn_readfirstlane(bx1 >> 1);
    const int sy0 = __builtin_amdgcn_readfirstlane(by0 >> 1);
    const int sy1 = __builtin_amdgcn_readfirstlane(by1 >> 1);
    const int sz0 = __builtin_amdgcn_readfirstlane(bz0 >> 1);
    const int sz1 = __builtin_amdgcn_readfirstlane(bz1 >> 1);

    const float4* cp = spts + cset*NPTS;
    const int*    cs = cellStart + cset*CS_STRIDE;

    float bd = __builtin_inff(); int bi = 0;

    // one candidate evaluation: bsq recomputed with EXACT rn chain; idx from .w
    #define EVAL(c4)                                                             \
    {                                                                            \
        float bsq = __fadd_rn(__fadd_rn(__fmul_rn((c4).x,(c4).x),                \
                                        __fmul_rn((c4).y,(c4).y)),               \
                              __fmul_rn((c4).z,(c4).z));                         \
        float tt = fmaf(az, (c4).z, fmaf(ay, (c4).y, __fmul_rn(ax, (c4).x)));    \
        float dd = fmaf(-2.0f, tt, __fadd_rn(aw, bsq));                          \
        int cix = __float_as_int((c4).w);                                        \
        bool bet = (dd < bd) || (dd == bd && cix < bi);                          \
        bd = bet ? dd : bd; bi = bet ? cix : bi;                                 \
    }

    // stride-8 scan of [j0,j1), 4x unrolled batched loads for MLP
    #define SCAN_RANGE(j0, j1)                                                   \
    {                                                                            \
        int j = (j0) + sub;                                                      \
        for (; j + 24 < (j1); j += 32) {                                         \
            float4 c0 = cp[j];                                                   \
            float4 c1 = cp[j+8];                                                 \
            float4 c2 = cp[j+16];                                                \
            float4 c3 = cp[j+24];                                                \
            EVAL(c0); EVAL(c1); EVAL(c2); EVAL(c3);                              \
        }                                                                        \
        for (; j < (j1); j += 8) {                                               \
            float4 c4 = cp[j];                                                   \
            EVAL(c4);                                                            \
        }                                                                        \
    }

    // seed window around the wave's sorted position (Morton locality)
    {
        int s0 = qbase + 4 - 80; if (s0 < 0) s0 = 0;
        int e0 = s0 + 160;       if (e0 > NPTS) { e0 = NPTS; s0 = e0 - 160; }
        s0 = __builtin_amdgcn_readfirstlane(s0);
        e0 = __builtin_amdgcn_readfirstlane(e0);
        SCAN_RANGE(s0, e0);
    }

    // superblock (2x2x2 cells, width 1.0) Chebyshev shells outward
    for (int s = 0; s <= 8; ++s) {
        int zlo = max(0, sz0 - s), zhi = min(SGRID-1, sz1 + s);
        int ylo = max(0, sy0 - s), yhi = min(SGRID-1, sy1 + s);
        int xlo = max(0, sx0 - s), xhi = min(SGRID-1, sx1 + s);
        for (int scz = zlo; scz <= zhi; ++scz) {
            int cdz = max(0, max(sz0 - scz, scz - sz1));
            float lo = (scz == 0)       ? -1e30f : (GLO + (float)(scz*2    )*GH);
            float hi = (scz == SGRID-1) ?  1e30f : (GLO + (float)(scz*2 + 2)*GH);
            float dzz = fmaxf(0.0f, fmaxf(lo - az, az - hi));
            float dz2 = __fmul_rn(dzz, dzz);
            for (int scy = ylo; scy <= yhi; ++scy) {
                int cdy = max(cdz, max(0, max(sy0 - scy, scy - sy1)));
                if (cdy > s) continue;
                lo = (scy == 0)       ? -1e30f : (GLO + (float)(scy*2    )*GH);
                hi = (scy == SGRID-1) ?  1e30f : (GLO + (float)(scy*2 + 2)*GH);
                float dyy = fmaxf(0.0f, fmaxf(lo - ay, ay - hi));
                float dyz2 = fmaf(dyy, dyy, dz2);
                int sbyz = (spr3(scy)<<1) | (spr3(scz)<<2);
                for (int scx = xlo; scx <= xhi; ++scx) {
                    int cd = max(cdy, max(0, max(sx0 - scx, scx - sx1)));
                    if (cd != s) continue;
                    lo = (scx == 0)       ? -1e30f : (GLO + (float)(scx*2    )*GH);
                    hi = (scx == SGRID-1) ?  1e30f : (GLO + (float)(scx*2 + 2)*GH);
                    float dxx = fmaxf(0.0f, fmaxf(lo - ax, ax - hi));
                    float lb = fmaf(dxx, dxx, dyz2);
                    if (__ballot(fmaf(0.995f, lb, -3e-4f) <= bd) == 0ULL) continue;
                    int sb = spr3(scx) | sbyz;
                    int j0 = __builtin_amdgcn_readfirstlane(cs[sb<<3]);
                    int j1 = __builtin_amdgcn_readfirstlane(cs[(sb+1)<<3]);
                    SCAN_RANGE(j0, j1);
                }
            }
        }
        float wmax = bd;
        #pragma unroll
        for (int m = 32; m; m >>= 1) wmax = fmaxf(wmax, __shfl_xor(wmax, m, 64));
        float rs = (float)s;                  // unvisited: Euclid >= s * 1.0
        if (fmaf(0.995f, rs*rs, -3e-4f) > wmax) break;
        if (xlo == 0 && ylo == 0 && zlo == 0 &&
            xhi == SGRID-1 && yhi == SGRID-1 && zhi == SGRID-1) break; // grid covered
    }

    #undef SCAN_RANGE
    #undef EVAL

    // reduce the 8 sub-lanes of each query: lex-min (d, orig_idx)
    #pragma unroll
    for (int m = 1; m < 8; m <<= 1) {
        float od = __shfl_xor(bd, m, 64);
        int   oi = __shfl_xor(bi, m, 64);
        bool bet = (od < bd) || (od == bd && oi < bi);
        bd = bet ? od : bd; bi = bet ? oi : bi;
    }

    if (sub == 0) {
        int off  = dir ? 32768 : 0;
        int slot = b*NPTS + qorig;
        out[off + slot]         = bd;
        out[65536 + off + slot] = (float)bi;
    }
}

// fallback (no/small ws): brute force, exact chain
__global__ __launch_bounds__(256) void nn_full(
    const float* __restrict__ xyz1, const float* __restrict__ xyz2,
    float* __restrict__ out)
{
    int qid = blockIdx.x*256 + threadIdx.x;
    int dir = qid >> 15;
    int q15 = qid & 32767;
    const float* qsrc = dir ? xyz2 : xyz1;
    float ax = qsrc[q15*3+0], ay = qsrc[q15*3+1], az = qsrc[q15*3+2];
    float asq = __fadd_rn(__fadd_rn(__fmul_rn(ax,ax), __fmul_rn(ay,ay)), __fmul_rn(az,az));
    const float* cp = (dir ? xyz1 : xyz2) + (size_t)(q15 & NPTS)*3;
    float bd = 3.402823466e+38f; int bi = 0;
    for (int j = 0; j < NPTS; ++j) {
        float bx = cp[3*j+0], by = cp[3*j+1], bz = cp[3*j+2];
        float bsq = __fadd_rn(__fadd_rn(__fmul_rn(bx,bx), __fmul_rn(by,by)), __fmul_rn(bz,bz));
        float tt = fmaf(az, bz, fmaf(ay, by, __fmul_rn(ax, bx)));
        float d = fmaf(-2.0f, tt, __fadd_rn(asq, bsq));
        if (d < bd) { bd = d; bi = j; }
    }
    int off = dir ? 32768 : 0;
    out[off + q15]         = bd;
    out[65536 + off + q15] = (float)bi;
}

extern "C" void kernel_launch(void* const* d_in, const int* in_sizes, int n_in,
                              void* d_out, int out_size, void* d_ws, size_t ws_size,
                              hipStream_t stream) {
    const float* xyz1 = (const float*)d_in[0];
    const float* xyz2 = (const float*)d_in[1];
    float* out = (float*)d_out;

    const size_t off_spts = 0;
    const size_t off_cs   = 1048576;
    const size_t off_hist = 1114128;
    const size_t off_cur  = 1179664;
    const size_t need     = 1245200;

    if (d_ws != nullptr && ws_size >= need) {
        float4* spts = (float4*)((char*)d_ws + off_spts);
        int* cstart  = (int*)((char*)d_ws + off_cs);
        int* hist    = (int*)((char*)d_ws + off_hist);
        int* cursor  = (int*)((char*)d_ws + off_cur);
        zero_hist   <<<64,  256, 0, stream>>>(hist);
        bin_kernel  <<<256, 256, 0, stream>>>(xyz1, xyz2, hist);
        scan_kernel <<<4,  1024, 0, stream>>>(hist, cstart, cursor);
        scatter_kernel<<<256,256,0, stream>>>(xyz1, xyz2, cursor, spts);
        nn_kernel   <<<2048, 256, 0, stream>>>(spts, cstart, out);
    } else {
        nn_full<<<65536/256, 256, 0, stream>>>(xyz1, xyz2, out);
    }
}